// Round 6
// baseline (454.388 us; speedup 1.0000x reference)
//
#include <hip/hip_runtime.h>
#include <hip/hip_bf16.h>
#include <math.h>

#define DM 768
#define NH 12
#define DH 64
#define DMLP 3072
#define BATCH 8
#define SEQ 1024
#define NTOK (BATCH*SEQ)
#define QKVN (3*DM)
#define LN_EPS 1e-5f

typedef __hip_bfloat16 bf16;
typedef __attribute__((ext_vector_type(8))) short bf16x8;
typedef __attribute__((ext_vector_type(4))) float f32x4;

#define MFMA16(a,b,c) __builtin_amdgcn_mfma_f32_16x16x32_bf16((a),(b),(c),0,0,0)

__device__ __forceinline__ float us2f(unsigned short u){
    unsigned int i = ((unsigned int)u) << 16; float f; __builtin_memcpy(&f, &i, 4); return f;
}
__device__ __forceinline__ short f2bs(float f){
    bf16 h = __float2bfloat16(f); short s; __builtin_memcpy(&s, &h, 2); return s;
}

// gelu_new(x) = x * sigmoid(2c(x + 0.044715 x^3)), c = sqrt(2/pi). ~7 VALU ops.
__device__ __forceinline__ float gelu_f(float x){
    float y = 1.5957691216057308f*(x + 0.044715f*x*x*x);
    return x * __builtin_amdgcn_rcpf(1.0f + __expf(-y));
}

// async 16B global->LDS. LDS dest = wave-uniform base + lane*16 (fixed linear).
__device__ __forceinline__ void gload16(const void* g, void* l){
    __builtin_amdgcn_global_load_lds(
        (const __attribute__((address_space(1))) void*)g,
        (__attribute__((address_space(3))) void*)l, 16, 0, 0);
}

// ---------------- transpose + fp32->bf16 convert: out[N][K] = in[K][N] ----------------
__global__ __launch_bounds__(256) void transpose_cvt(const float* __restrict__ in,
                                                     short* __restrict__ out,
                                                     int K, int N)
{
    __shared__ float t[32][33];
    int n0 = blockIdx.x*32, k0 = blockIdx.y*32;
    int tx = threadIdx.x & 31, ty = threadIdx.x >> 5;
    #pragma unroll
    for (int i = 0; i < 32; i += 8)
        t[ty+i][tx] = in[(size_t)(k0+ty+i)*N + n0+tx];
    __syncthreads();
    #pragma unroll
    for (int i = 0; i < 32; i += 8)
        out[(size_t)(n0+ty+i)*K + k0+tx] = f2bs(t[tx][ty+i]);
}

// qkv weights: W_{q,k,v}[h][k][e] -> wqkvT[n = which*768 + h*64 + e][k], bf16
__global__ __launch_bounds__(256) void transpose_cvt_qkv(const float* __restrict__ Wq,
                                                         const float* __restrict__ Wk,
                                                         const float* __restrict__ Wv,
                                                         short* __restrict__ out)
{
    __shared__ float t[32][33];
    int zz = blockIdx.z;
    int which = zz / 12, h = zz % 12;
    const float* in = (which == 0 ? Wq : which == 1 ? Wk : Wv) + (size_t)h*DM*DH;
    short* o = out + ((size_t)which*DM + h*DH)*DM;
    int n0 = blockIdx.x*32, k0 = blockIdx.y*32;
    int tx = threadIdx.x & 31, ty = threadIdx.x >> 5;
    #pragma unroll
    for (int i = 0; i < 32; i += 8)
        t[ty+i][tx] = in[(size_t)(k0+ty+i)*DH + n0+tx];
    __syncthreads();
    #pragma unroll
    for (int i = 0; i < 32; i += 8)
        o[(size_t)(n0+ty+i)*DM + k0+tx] = f2bs(t[tx][ty+i]);
}

// concat b_Q|b_K|b_V -> [2304] fp32
__global__ __launch_bounds__(256) void prep_qkv_bias(const float* bQ, const float* bK, const float* bV,
                                                     float* __restrict__ out)
{
    int idx = blockIdx.x*256 + threadIdx.x;
    if (idx >= QKVN) return;
    int which = idx / DM, hc = idx % DM;
    const float* b = (which == 0) ? bQ : ((which == 1) ? bK : bV);
    out[idx] = b[hc];
}

// v_rm [8192][768] bf16 -> vT [(b*12+h)*64 + d][1024] bf16
__global__ __launch_bounds__(256) void transpose_v(const short* __restrict__ v_rm,
                                                   short* __restrict__ vT)
{
    __shared__ short t[64][65];
    int st = blockIdx.x, h = blockIdx.y, b = blockIdx.z;
    int tok = threadIdx.x >> 2, seg = (threadIdx.x & 3)*16;
    const short* src = v_rm + (size_t)(b*SEQ + st*64 + tok)*DM + h*DH + seg;
    bf16x8 a0 = *(const bf16x8*)src;
    bf16x8 a1 = *(const bf16x8*)(src + 8);
    #pragma unroll
    for (int i = 0; i < 8; i++) t[seg + i][tok]     = a0[i];
    #pragma unroll
    for (int i = 0; i < 8; i++) t[seg + 8 + i][tok] = a1[i];
    __syncthreads();
    int d = threadIdx.x >> 2; int sk = (threadIdx.x & 3)*16;
    short* dst = vT + ((size_t)(b*NH + h)*DH + d)*SEQ + st*64 + sk;
    bf16x8 w0, w1;
    #pragma unroll
    for (int i = 0; i < 8; i++) w0[i] = t[d][sk + i];
    #pragma unroll
    for (int i = 0; i < 8; i++) w1[i] = t[d][sk + 8 + i];
    *(bf16x8*)dst = w0;
    *(bf16x8*)(dst + 8) = w1;
}

// ---------------- layernorm (fp32 in, bf16 out) ----------------
__device__ __forceinline__ float block_reduce_sum(float v, float* buf){
    int tid = threadIdx.x;
    buf[tid] = v; __syncthreads();
    for (int s = 128; s > 0; s >>= 1){
        if (tid < s) buf[tid] += buf[tid + s];
        __syncthreads();
    }
    float r = buf[0]; __syncthreads();
    return r;
}

__global__ __launch_bounds__(256) void ln_kernel(const float* __restrict__ x,
                                                 const float* __restrict__ w,
                                                 const float* __restrict__ b,
                                                 short* __restrict__ out)
{
    __shared__ float buf[256];
    int row = blockIdx.x, tid = threadIdx.x;
    const float* xr = x + (size_t)row*DM;
    float v[3];
    float s = 0.f, s2 = 0.f;
    #pragma unroll
    for (int i = 0; i < 3; i++){
        float t = xr[tid + 256*i];
        v[i] = t; s += t; s2 += t*t;
    }
    float sum  = block_reduce_sum(s,  buf);
    float sum2 = block_reduce_sum(s2, buf);
    float mean = sum * (1.0f/DM);
    float var  = sum2 * (1.0f/DM) - mean*mean;
    float rstd = rsqrtf(var + LN_EPS);
    #pragma unroll
    for (int i = 0; i < 3; i++){
        int c = tid + 256*i;
        out[(size_t)row*DM + c] = f2bs((v[i] - mean)*rstd*w[c] + b[c]);
    }
}

// ---------------- MFMA B^T GEMM, 128x128 tile, BK=32 double-buffered ----------------
// C[M,N] = A[M,K] @ Bt[N,K]^T. One barrier per K-step; next tile's global_load_lds
// issued before frag-reads+MFMA so the barrier drain overlaps compute.
// EPI: 1=gelu. RES: 2=fp32 residual. OUT: 0 bf16, 1 fp32.
// SPLITV: cols<1536 -> Cp (stride 1536), cols>=1536 -> Cp2 (stride 768), both bf16.
template<int EPI, int RES, int OUT, int SPLITV>
__global__ __launch_bounds__(256) void gemm_bt(const short* __restrict__ A,
                                               const short* __restrict__ Bt,
                                               const float* __restrict__ bias,
                                               const void* __restrict__ resp,
                                               void* __restrict__ Cp,
                                               void* __restrict__ Cp2,
                                               int N, int K)
{
    __shared__ alignas(16) short As[2][128*32];
    __shared__ alignas(16) short Bs[2][128*32];
    int tid = threadIdx.x, lane = tid & 63, w = tid >> 6;
    int l15 = lane & 15, quad = lane >> 4;
    int m_base = blockIdx.y*128, n_base = blockIdx.x*128;

    // staging: chunk = 16 rows x 32 shorts (1KB); wave w stages chunks {2w,2w+1} of A and B.
    // lane -> row r4=lane>>2 within chunk, stored seg lane&3 holds global seg (lane&3)^(r4&3).
    int r4 = lane >> 2;
    int sG = ((lane & 3) ^ (r4 & 3)) * 8;
    const short* gA0 = A  + (size_t)(m_base + 32*w      + r4)*K + sG;
    const short* gA1 = A  + (size_t)(m_base + 32*w + 16 + r4)*K + sG;
    const short* gB0 = Bt + (size_t)(n_base + 32*w      + r4)*K + sG;
    const short* gB1 = Bt + (size_t)(n_base + 32*w + 16 + r4)*K + sG;

    int mrow0 = (w >> 1)*64, ncol0 = (w & 1)*64;
    f32x4 acc[4][4] = {};

    // prologue: stage k-step 0 into buf 0
    gload16(gA0, &As[0][(2*w)*512]);
    gload16(gA1, &As[0][(2*w+1)*512]);
    gload16(gB0, &Bs[0][(2*w)*512]);
    gload16(gB1, &Bs[0][(2*w+1)*512]);

    int nk = K >> 5;
    for (int ki = 0; ki < nk; ki++){
        __syncthreads();   // drains stage(ki) (vmcnt0) + prior iter's LDS reads
        int cur = ki & 1, nxt = cur ^ 1;
        if (ki + 1 < nk){
            int off = (ki + 1) << 5;
            gload16(gA0 + off, &As[nxt][(2*w)*512]);
            gload16(gA1 + off, &As[nxt][(2*w+1)*512]);
            gload16(gB0 + off, &Bs[nxt][(2*w)*512]);
            gload16(gB1 + off, &Bs[nxt][(2*w+1)*512]);
        }
        bf16x8 af[4], bfr[4];
        #pragma unroll
        for (int i = 0; i < 4; i++){
            int m = mrow0 + 16*i + l15;
            af[i] = *(const bf16x8*)(&As[cur][m*32 + ((quad ^ (m & 3))*8)]);
        }
        #pragma unroll
        for (int j = 0; j < 4; j++){
            int n = ncol0 + 16*j + l15;
            bfr[j] = *(const bf16x8*)(&Bs[cur][n*32 + ((quad ^ (n & 3))*8)]);
        }
        #pragma unroll
        for (int i = 0; i < 4; i++)
            #pragma unroll
            for (int j = 0; j < 4; j++)
                acc[i][j] = MFMA16(af[i], bfr[j], acc[i][j]);
    }

    #pragma unroll
    for (int i = 0; i < 4; i++){
        #pragma unroll
        for (int j = 0; j < 4; j++){
            #pragma unroll
            for (int r = 0; r < 4; r++){
                size_t row = (size_t)(m_base + mrow0 + 16*i + quad*4 + r);
                int    col = n_base + ncol0 + 16*j + l15;
                float v = acc[i][j][r] + bias[col];
                if (EPI == 1) v = gelu_f(v);
                if (RES == 2) v += ((const float*)resp)[row*N + col];
                if (SPLITV){
                    if (col < 1536) ((short*)Cp )[row*1536 + col]        = f2bs(v);
                    else            ((short*)Cp2)[row*768  + col - 1536] = f2bs(v);
                } else if (OUT == 0) ((short*)Cp)[row*N + col] = f2bs(v);
                else                 ((float*)Cp)[row*N + col] = v;
            }
        }
    }
}

// ---------------- thin MFMA GEMM: 128x64 tile, BK=32 double-buffered ----------------
template<int EPI, int RES, int OUT>
__global__ __launch_bounds__(256) void gemm_bt_thin(const short* __restrict__ A,
                                                    const short* __restrict__ Bt,
                                                    const float* __restrict__ bias,
                                                    const void* __restrict__ resp,
                                                    void* __restrict__ Cp,
                                                    int N, int K)
{
    __shared__ alignas(16) short As[2][128*32];
    __shared__ alignas(16) short Bs[2][64*32];
    int tid = threadIdx.x, lane = tid & 63, w = tid >> 6;
    int l15 = lane & 15, quad = lane >> 4;
    int m_base = blockIdx.y*128, n_base = blockIdx.x*64;

    int r4 = lane >> 2;
    int sG = ((lane & 3) ^ (r4 & 3)) * 8;
    const short* gA0 = A  + (size_t)(m_base + 32*w      + r4)*K + sG;
    const short* gA1 = A  + (size_t)(m_base + 32*w + 16 + r4)*K + sG;
    const short* gB0 = Bt + (size_t)(n_base + 16*w      + r4)*K + sG;

    f32x4 acc[2][4] = {};

    gload16(gA0, &As[0][(2*w)*512]);
    gload16(gA1, &As[0][(2*w+1)*512]);
    gload16(gB0, &Bs[0][w*512]);

    int nk = K >> 5;
    for (int ki = 0; ki < nk; ki++){
        __syncthreads();
        int cur = ki & 1, nxt = cur ^ 1;
        if (ki + 1 < nk){
            int off = (ki + 1) << 5;
            gload16(gA0 + off, &As[nxt][(2*w)*512]);
            gload16(gA1 + off, &As[nxt][(2*w+1)*512]);
            gload16(gB0 + off, &Bs[nxt][w*512]);
        }
        bf16x8 af[2], bfr[4];
        #pragma unroll
        for (int i = 0; i < 2; i++){
            int m = 32*w + 16*i + l15;
            af[i] = *(const bf16x8*)(&As[cur][m*32 + ((quad ^ (m & 3))*8)]);
        }
        #pragma unroll
        for (int j = 0; j < 4; j++){
            int n = 16*j + l15;
            bfr[j] = *(const bf16x8*)(&Bs[cur][n*32 + ((quad ^ (n & 3))*8)]);
        }
        #pragma unroll
        for (int i = 0; i < 2; i++)
            #pragma unroll
            for (int j = 0; j < 4; j++)
                acc[i][j] = MFMA16(af[i], bfr[j], acc[i][j]);
    }

    #pragma unroll
    for (int i = 0; i < 2; i++){
        #pragma unroll
        for (int j = 0; j < 4; j++){
            #pragma unroll
            for (int r = 0; r < 4; r++){
                size_t row = (size_t)(m_base + 32*w + 16*i + quad*4 + r);
                int    col = n_base + 16*j + l15;
                float v = acc[i][j][r] + bias[col];
                if (EPI == 1) v = gelu_f(v);
                if (RES == 2) v += ((const float*)resp)[row*N + col];
                if (OUT == 0) ((short*)Cp)[row*N + col] = f2bs(v);
                else          ((float*)Cp)[row*N + col] = v;
            }
        }
    }
}

// ---------------- MFMA flash attention v3: K/V double-buffered ----------------
// qk [8192][1536]: cols [0,768) Q, [768,1536) K (col h*64+e). vT [(b*12+h)*64+d][1024].
// block = (pair p, h, b): processes q-tiles p and 15-p (17 kt-iters, balanced).
__global__ __launch_bounds__(256) void flash_attn(const short* __restrict__ qk,
                                                  const short* __restrict__ vT,
                                                  short* __restrict__ z)
{
    __shared__ alignas(16) short U[4608];        // Q tile [64][64] swz / Ps [4][16][72]
    __shared__ alignas(16) short Ks[2][64*64];   // swizzled
    __shared__ alignas(16) short Vt[2][64*64];   // swizzled, rows = d
    int p = blockIdx.x, h = blockIdx.y, b = blockIdx.z;
    int tid = threadIdx.x, lane = tid & 63, w = tid >> 6;
    int l15 = lane & 15, quad = lane >> 4;
    int r8 = lane >> 3, u8 = lane & 7;
    int useg = (u8 ^ r8) * 8;

    for (int phase = 0; phase < 2; phase++){
        int qt = phase ? (15 - p) : p;

        __syncthreads();   // prior phase's LDS readers done
        // stage Q tile + KV(0) into buf 0
        #pragma unroll
        for (int c = 0; c < 2; c++){
            const short* g = qk + (size_t)(b*SEQ + qt*64 + 16*w + 8*c + r8)*1536 + h*DH + useg;
            gload16(g, U + (2*w + c)*512);
            const short* gk = qk + (size_t)(b*SEQ + 16*w + 8*c + r8)*1536 + DM + h*DH + useg;
            gload16(gk, &Ks[0][(2*w + c)*512]);
            const short* gv = vT + ((size_t)(b*NH + h)*DH + 16*w + 8*c + r8)*SEQ + useg;
            gload16(gv, &Vt[0][(2*w + c)*512]);
        }
        __syncthreads();   // drain

        bf16x8 aq[2];
        #pragma unroll
        for (int kk = 0; kk < 2; kk++)
            aq[kk] = *(const bf16x8*)(U + (16*w + l15)*64 + (((4*kk + quad) ^ (l15 & 7))*8));

        float m_state[4] = {-1e30f,-1e30f,-1e30f,-1e30f};
        float l_state[4] = {0.f,0.f,0.f,0.f};
        f32x4 o_acc[4] = {};
        int rg = qt*64 + w*16 + quad*4;

        for (int kt = 0; kt <= qt; ++kt){
            int cur = kt & 1, nxt = cur ^ 1;
            if (kt < qt){   // prefetch next K/V tile (overlaps this iter's compute)
                #pragma unroll
                for (int c = 0; c < 2; c++){
                    const short* gk = qk + (size_t)(b*SEQ + (kt+1)*64 + 16*w + 8*c + r8)*1536 + DM + h*DH + useg;
                    gload16(gk, &Ks[nxt][(2*w + c)*512]);
                    const short* gv = vT + ((size_t)(b*NH + h)*DH + 16*w + 8*c + r8)*SEQ + (kt+1)*64 + useg;
                    gload16(gv, &Vt[nxt][(2*w + c)*512]);
                }
            }

            // S = Q K^T (16 q x 64 key per wave)
            f32x4 s[4] = {};
            #pragma unroll
            for (int kk = 0; kk < 2; kk++){
                int swz = ((4*kk + quad) ^ (l15 & 7)) * 8;
                #pragma unroll
                for (int j = 0; j < 4; j++){
                    bf16x8 bk = *(const bf16x8*)(&Ks[cur][(16*j + l15)*64 + swz]);
                    s[j] = MFMA16(aq[kk], bk, s[j]);
                }
            }

            // scale + causal mask (diagonal tile only)
            bool diag = (kt == qt);
            #pragma unroll
            for (int j = 0; j < 4; j++){
                int col_g = kt*64 + 16*j + l15;
                #pragma unroll
                for (int r = 0; r < 4; r++){
                    float v = s[j][r] * 0.125f;
                    if (diag && col_g > rg + r) v = -1e30f;
                    s[j][r] = v;
                }
            }

            // online softmax (rows = quad*4 + r; reduce across 16 lanes of quad-group)
            #pragma unroll
            for (int r = 0; r < 4; r++){
                float mx = fmaxf(fmaxf(s[0][r], s[1][r]), fmaxf(s[2][r], s[3][r]));
                #pragma unroll
                for (int d = 1; d < 16; d <<= 1) mx = fmaxf(mx, __shfl_xor(mx, d, 64));
                float m_new = fmaxf(m_state[r], mx);
                float alpha = __expf(m_state[r] - m_new);
                m_state[r] = m_new;
                float rs = 0.f;
                #pragma unroll
                for (int j = 0; j < 4; j++){
                    float pv = __expf(s[j][r] - m_new);
                    s[j][r] = pv; rs += pv;
                }
                #pragma unroll
                for (int d = 1; d < 16; d <<= 1) rs += __shfl_xor(rs, d, 64);
                l_state[r] = l_state[r]*alpha + rs;
                #pragma unroll
                for (int j = 0; j < 4; j++) o_acc[j][r] *= alpha;
            }

            // P -> LDS (bf16, wave-private region of U; stride 72)
            #pragma unroll
            for (int j = 0; j < 4; j++)
                #pragma unroll
                for (int r = 0; r < 4; r++)
                    U[w*1152 + (quad*4 + r)*72 + 16*j + l15] = f2bs(s[j][r]);

            // O += P V
            #pragma unroll
            for (int kk = 0; kk < 2; kk++){
                bf16x8 ap = *(const bf16x8*)(U + w*1152 + l15*72 + 32*kk + quad*8);
                int swz = ((4*kk + quad) ^ (l15 & 7)) * 8;
                #pragma unroll
                for (int j = 0; j < 4; j++){
                    bf16x8 bv = *(const bf16x8*)(&Vt[cur][(16*j + l15)*64 + swz]);
                    o_acc[j] = MFMA16(ap, bv, o_acc[j]);
                }
            }

            __syncthreads();   // drain stage(kt+1); protect buf[cur] + U for next writers
        }

        // epilogue: z[row][h*64 + col] = o / l
        #pragma unroll
        for (int r = 0; r < 4; r++){
            float inv_l = 1.0f / l_state[r];
            size_t row = (size_t)(b*SEQ + rg + r);
            #pragma unroll
            for (int j = 0; j < 4; j++)
                z[row*DM + h*DH + 16*j + l15] = f2bs(o_acc[j][r] * inv_l);
        }
    }
}

// ---------------- launch ----------------
// ws map (59,778,048 B, lifetime-aliased):
//   A0 [0, 3538944)          wqkvT               -> WinT (A0+A1) after O-gemm
//   A1 [3538944, 4718592)    WOT
//   A2 [4718592, 4727808)    bias_qkv fp32
//   A3 [4727808, 29893632)   qk bf16 [qkv-gemm -> flash] -> hidden chunk (25.17MB) [MLP]
//   A4 [29893632, 42476544)  v_rm [qkv-gemm -> transpose_v] -> zbuf [flash -> O-gemm]
//   A5 [42476544, 55059456)  ln1o [ln1 -> qkv-gemm] -> vT [transpose_v -> flash] -> ln2o [MLP]
//   A6 [55059456, 59778048)  WoutT
// resid_mid lives in d_out (fp32): O-gemm writes it, ln2 reads it, final gemm adds in place.
extern "C" void kernel_launch(void* const* d_in, const int* in_sizes, int n_in,
                              void* d_out, int out_size, void* d_ws, size_t ws_size,
                              hipStream_t stream)
{
    const float* resid_pre = (const float*)d_in[0];
    const float* W_Q  = (const float*)d_in[1];
    const float* W_K  = (const float*)d_in[2];
    const float* W_V  = (const float*)d_in[3];
    const float* W_O  = (const float*)d_in[4];
    const float* b_Q  = (const float*)d_in[5];
    const float* b_K  = (const float*)d_in[6];
    const float* b_V  = (const float*)d_in[7];
    const float* b_O  = (const float*)d_in[8];
    const float* ln1w = (const float*)d_in[9];
    const float* ln1b = (const float*)d_in[10];
    const float* ln2w = (const float*)d_in[11];
    const float* ln2b = (const float*)d_in[12];
    const float* W_in = (const float*)d_in[13];
    const float* b_in = (const float*)d_in[14];
    const float* W_out= (const float*)d_in[15];
    const float* b_out= (const float*)d_in[16];

    char* ws = (char*)d_ws;
    short* wqkvT    = (short*)(ws);
    short* WOT      = (short*)(ws + 3538944);
    float* bias_qkv = (float*)(ws + 4718592);
    short* WinT     = (short*)(ws);             // after O-gemm
    short* qk       = (short*)(ws + 4727808);   // A3
    short* hidden   = (short*)(ws + 4727808);   // A3 after flash
    short* v_rm     = (short*)(ws + 29893632);  // A4
    short* zbuf     = (short*)(ws + 29893632);  // A4 after transpose_v
    short* ln1o     = (short*)(ws + 42476544);  // A5
    short* vT       = (short*)(ws + 42476544);  // A5 after qkv-gemm
    short* ln2o     = (short*)(ws + 42476544);  // A5 after flash
    short* WoutT    = (short*)(ws + 55059456);  // A6

    // prep
    transpose_cvt_qkv<<<dim3(2, 24, 36), dim3(256), 0, stream>>>(W_Q, W_K, W_V, wqkvT);
    prep_qkv_bias<<<dim3(9), dim3(256), 0, stream>>>(b_Q, b_K, b_V, bias_qkv);
    transpose_cvt<<<dim3(24, 24), dim3(256), 0, stream>>>(W_O,   WOT,   DM,   DM);
    transpose_cvt<<<dim3(24, 96), dim3(256), 0, stream>>>(W_out, WoutT, DMLP, DM);

    // ln1 + QKV projection (split: Q,K -> qk[.][1536], V -> v_rm[.][768])
    ln_kernel<<<dim3(NTOK), dim3(256), 0, stream>>>(resid_pre, ln1w, ln1b, ln1o);
    gemm_bt<0,0,0,1><<<dim3(QKVN/128, NTOK/128), dim3(256), 0, stream>>>(
        ln1o, wqkvT, bias_qkv, nullptr, qk, v_rm, QKVN, DM);

    // V transpose then flash attention
    transpose_v<<<dim3(SEQ/64, NH, BATCH), dim3(256), 0, stream>>>(v_rm, vT);
    flash_attn<<<dim3(SEQ/128, NH, BATCH), dim3(256), 0, stream>>>(qk, vT, zbuf);

    // O projection + residual(resid_pre fp32) -> d_out fp32
    gemm_bt_thin<0,2,1><<<dim3(DM/64, NTOK/128), dim3(256), 0, stream>>>(
        zbuf, WOT, b_O, resid_pre, d_out, DM, DM);

    // W_in transpose (A0/A1 dead)
    transpose_cvt<<<dim3(96, 24), dim3(256), 0, stream>>>(W_in, WinT, DM, DMLP);

    // ln2 on d_out (fp32)
    ln_kernel<<<dim3(NTOK), dim3(256), 0, stream>>>((const float*)d_out, ln2w, ln2b, ln2o);

    // MLP in 2 chunks of 4096 rows; final gemm reads+writes d_out in place
    for (int chunk = 0; chunk < 2; chunk++){
        size_t r0 = (size_t)chunk * 4096;
        gemm_bt<1,0,0,0><<<dim3(DMLP/128, 4096/128), dim3(256), 0, stream>>>(
            ln2o + r0*DM, WinT, b_in, nullptr, hidden, nullptr, DMLP, DM);
        gemm_bt_thin<0,2,1><<<dim3(DM/64, 4096/128), dim3(256), 0, stream>>>(
            hidden, WoutT, b_out, (float*)d_out + r0*DM, (float*)d_out + r0*DM, DM, DMLP);
    }
}